// Round 7
// baseline (395.449 us; speedup 1.0000x reference)
//
#include <hip/hip_runtime.h>
#include <hip/hip_bf16.h>

typedef unsigned short u16;
typedef unsigned int u32;
typedef __bf16 bf16x8 __attribute__((ext_vector_type(8)));
typedef float f32x4 __attribute__((ext_vector_type(4)));

#define MFMA16(a, b, c) __builtin_amdgcn_mfma_f32_16x16x32_bf16((a), (b), (c), 0, 0, 0)

static __device__ __forceinline__ float bfbits2f(u32 b) {
    union { u32 u; float f; } c; c.u = b << 16; return c.f;
}
// round-to-nearest-even f32 -> bf16 bits
static __device__ __forceinline__ u32 f2bfbits(float f) {
    union { float f; u32 u; } c; c.f = f;
    return (c.u + 0x7FFFu + ((c.u >> 16) & 1u)) >> 16;
}
// exact for small integers (|v| <= 255): low 16 mantissa bits are zero
static __device__ __forceinline__ u32 f2bfbits_exact(float f) {
    union { float f; u32 u; } c; c.f = f;
    return c.u >> 16;
}
// packed RNE f32x2 -> bf16x2 (v_cvt_pk_bf16_f32 on gfx950)
static __device__ __forceinline__ u32 pack_bf16x2(float lo, float hi) {
    float2 v; v.x = lo; v.y = hi;
    union { __hip_bfloat162 h; u32 u; } c;
    c.h = __float22bfloat162_rn(v);
    return c.u;  // low 16 = lo, high 16 = hi
}

// ---------------- batched JAX threefry2x32, key (0,42), 8 draws in lockstep.
// SoA across d=0..7 makes the 8 independent 60-op chains explicit -> the
// scheduler interleaves them (no dependent-latency serialization) and the
// round constants stay live in regs instead of being rematerialized.
// Partitionable mode (HW-verified R4): counter=(0,idx), bits=x0^x1,
// uniform in [-0.99999994, 1), XLA Giles erfinv; returns p*u = erfinv(u).
static __device__ __forceinline__ void noise_pu8(const u32* __restrict__ idx,
                                                 float* __restrict__ pu) {
    const u32 K1 = 42u, K2 = 0x1BD11BF0u;  // 0x1BD11BDA ^ 42
    u32 x0[8], x1[8];
#pragma unroll
    for (int d = 0; d < 8; d++) { x0[d] = 0u; x1[d] = idx[d] + K1; }
#define TFR(R)                                            \
    _Pragma("unroll") for (int d = 0; d < 8; d++) {       \
        x0[d] += x1[d];                                   \
        x1[d] = __builtin_rotateleft32(x1[d], R) ^ x0[d]; \
    }
#define INJ(A, B)                                         \
    _Pragma("unroll") for (int d = 0; d < 8; d++) {       \
        x0[d] += (A); x1[d] += (B);                       \
    }
    TFR(13) TFR(15) TFR(26) TFR(6)  INJ(K1, K2 + 1u)
    TFR(17) TFR(29) TFR(16) TFR(24) INJ(K2, 2u)
    TFR(13) TFR(15) TFR(26) TFR(6)  INJ(0u, K1 + 3u)
    TFR(17) TFR(29) TFR(16) TFR(24) INJ(K1, K2 + 4u)
    TFR(13) TFR(15) TFR(26) TFR(6)  INJ(K2, 5u)
#undef TFR
#undef INJ
#pragma unroll
    for (int d = 0; d < 8; d++) {
        u32 bits = x0[d] ^ x1[d];
        float f = __uint_as_float((bits >> 9) | 0x3F800000u) - 1.0f;  // [0,1)
        float u = fmaf(f, 2.0f, -0.99999994f);
        u = fmaxf(-0.99999994f, u);
        float t = fmaf(-u, u, 1.0f);   // exact 1-u^2 (single rounding)
        float lg = __logf(t);          // native v_log_f32 path
        float p;
        if (lg > -5.0f) {              // w = -lg < 5
            float z = fmaf(lg, -1.0f, -2.5f);
            p = 2.81022636e-08f;
            p = fmaf(p, z, 3.43273939e-07f);
            p = fmaf(p, z, -3.5233877e-06f);
            p = fmaf(p, z, -4.39150654e-06f);
            p = fmaf(p, z, 0.00021858087f);
            p = fmaf(p, z, -0.00125372503f);
            p = fmaf(p, z, -0.00417768164f);
            p = fmaf(p, z, 0.246640727f);
            p = fmaf(p, z, 1.50140941f);
        } else {
            float z = sqrtf(-lg) - 3.0f;
            p = -0.000200214257f;
            p = fmaf(p, z, 0.000100950558f);
            p = fmaf(p, z, 0.00134934322f);
            p = fmaf(p, z, -0.00367342844f);
            p = fmaf(p, z, 0.00573950773f);
            p = fmaf(p, z, -0.0076224613f);
            p = fmaf(p, z, 0.00943887047f);
            p = fmaf(p, z, 1.00167406f);
            p = fmaf(p, z, 2.83297682f);
        }
        pu[d] = p * u;  // caller: fma(pu, 0.05*sqrt(2), logit)
    }
}

// ---------------- absmax over the 4 f32 tensors (u32 bit compare, sign stripped)
__global__ __launch_bounds__(256) void absmax_k(const float* __restrict__ h,
                                                const float* __restrict__ wq,
                                                const float* __restrict__ wk,
                                                const float* __restrict__ wv,
                                                u32* __restrict__ slots) {
    int t = blockIdx.y;
    const float* src = (t == 0) ? h : (t == 1) ? wq : (t == 2) ? wk : wv;
    int n4 = ((t == 0) ? 4096 * 1024 : 1024 * 1024) / 4;
    u32 mx = 0;
    int tid = threadIdx.x;
    for (int i = blockIdx.x * blockDim.x + tid; i < n4; i += gridDim.x * blockDim.x) {
        uint4 v = ((const uint4*)src)[i];
        mx = max(mx, v.x & 0x7FFFFFFFu);
        mx = max(mx, v.y & 0x7FFFFFFFu);
        mx = max(mx, v.z & 0x7FFFFFFFu);
        mx = max(mx, v.w & 0x7FFFFFFFu);
    }
    __shared__ u32 red[256];
    red[tid] = mx;
    __syncthreads();
    for (int s = 128; s > 0; s >>= 1) {
        if (tid < s) red[tid] = max(red[tid], red[tid + s]);
        __syncthreads();
    }
    if (tid == 0) atomicMax(&slots[t], red[0]);
}

// ---------------- merged pre-quantize: y=0 hidden (8-bit, + raw bf16 copy),
// y=1..3 weights (4-bit)
__global__ __launch_bounds__(256) void prequant_all(const float* __restrict__ hidden,
                                                    const float* __restrict__ wq,
                                                    const float* __restrict__ wk,
                                                    const float* __restrict__ wv,
                                                    u16* __restrict__ hq,
                                                    u16* __restrict__ hbf,
                                                    u16* __restrict__ wqi,
                                                    u16* __restrict__ wki,
                                                    u16* __restrict__ wvi,
                                                    const u32* __restrict__ slots) {
    int y = blockIdx.y;
    const float* src = (y == 0) ? hidden : (y == 1) ? wq : (y == 2) ? wk : wv;
    u16* dqi = (y == 0) ? hq : (y == 1) ? wqi : (y == 2) ? wki : wvi;
    u16* draw = (y == 0) ? hbf : nullptr;
    float qmax = (y == 0) ? 127.0f : 7.0f;
    int n8 = ((y == 0) ? 4096 * 1024 : 1024 * 1024) / 8;

    float amax = fmaxf(__uint_as_float(slots[y]), 1e-8f);
    float scale = amax / qmax;  // IEEE f32, matches np
    for (int i = blockIdx.x * blockDim.x + threadIdx.x; i < n8; i += gridDim.x * blockDim.x) {
        float4 a = ((const float4*)src)[2 * i];
        float4 b = ((const float4*)src)[2 * i + 1];
        float x[8] = {a.x, a.y, a.z, a.w, b.x, b.y, b.z, b.w};
        u16 qi[8], rw[8];
#pragma unroll
        for (int j = 0; j < 8; j++) {
            float q = fminf(fmaxf(rintf(x[j] / scale), -qmax), qmax);  // IEEE div + half-even
            qi[j] = (u16)f2bfbits_exact(q);
            rw[j] = (u16)f2bfbits(x[j]);
        }
        *(uint4*)(dqi + 8 * (size_t)i) = *(const uint4*)qi;
        if (draw) *(uint4*)(draw + 8 * (size_t)i) = *(const uint4*)rw;
    }
}

// ---------------- merged projection GEMMs: z=0 Q, z=1 K, z=2 V^T
// out[t,o] = oscale * sum_d A[t,d]*W[o,d]
__global__ __launch_bounds__(256) void qkv_gemm_all(const u16* __restrict__ hq,
                                                    const u16* __restrict__ hbf,
                                                    const u16* __restrict__ wqi,
                                                    const u16* __restrict__ wki,
                                                    const u16* __restrict__ wvi,
                                                    const u32* __restrict__ slots,
                                                    u16* __restrict__ Qb,
                                                    u16* __restrict__ Kb,
                                                    u16* __restrict__ Vtb) {
    __shared__ __align__(16) u16 As[64 * 40];
    __shared__ __align__(16) u16 Bs[64 * 40];
    int z = blockIdx.z;
    const u16* A  = (z < 2) ? hq : hbf;
    const u16* Bw = (z == 0) ? wqi : (z == 1) ? wki : wvi;
    u16* outp     = (z == 0) ? Qb : (z == 1) ? Kb : Vtb;
    int transOut = (z == 2);
    float s_a = fmaxf(__uint_as_float(slots[0]), 1e-8f) / 127.0f;
    float s_w = fmaxf(__uint_as_float(slots[z + 1]), 1e-8f) / 7.0f;
    float oscale = (z < 2) ? (s_a * s_w) : s_w;

    int tid = threadIdx.x;
    int srow = tid >> 2, scol = (tid & 3) * 8;
    int mbase = blockIdx.x * 64, nbase = blockIdx.y * 64;
    int lane = tid & 63, wv = tid >> 6;
    int quad = lane >> 4, l16 = lane & 15;

    f32x4 acc[4];
#pragma unroll
    for (int i = 0; i < 4; i++) acc[i] = (f32x4){0.f, 0.f, 0.f, 0.f};

    const u16* aptr = A + (size_t)(mbase + srow) * 1024 + scol;
    const u16* bptr = Bw + (size_t)(nbase + srow) * 1024 + scol;

    for (int k0 = 0; k0 < 1024; k0 += 32) {
        uint4 av = *(const uint4*)(aptr + k0);
        uint4 bv = *(const uint4*)(bptr + k0);
        __syncthreads();
        *(uint4*)(As + srow * 40 + scol) = av;
        *(uint4*)(Bs + srow * 40 + scol) = bv;
        __syncthreads();
        bf16x8 af = *(const bf16x8*)(As + (wv * 16 + l16) * 40 + quad * 8);
#pragma unroll
        for (int nt = 0; nt < 4; nt++) {
            bf16x8 bfr = *(const bf16x8*)(Bs + (nt * 16 + l16) * 40 + quad * 8);
            acc[nt] = MFMA16(af, bfr, acc[nt]);
        }
    }

#pragma unroll
    for (int nt = 0; nt < 4; nt++) {
#pragma unroll
        for (int r = 0; r < 4; r++) {
            float val = acc[nt][r] * oscale;
            int m = mbase + wv * 16 + quad * 4 + r;  // token
            int o = nbase + nt * 16 + l16;           // out-feature
            int b = m >> 10, s = m & 1023;
            int hh = o >> 6, dh = o & 63;
            size_t off = transOut ? (((size_t)(b * 16 + hh) * 64 + dh) * 1024 + s)
                                  : (((size_t)(b * 16 + hh) * 1024 + s) * 64 + dh);
            outp[off] = (u16)f2bfbits(val);
        }
    }
}

// ---------------- flash attention with inline threefry noise
// Q,K: [B,H,S,64] bf16; Vt: [B,H,64,S] bf16; mask: [B,1,1,S] f32; out f32.
// Fixed-reference softmax (M=0): logits bounded, exp cannot overflow.
// __launch_bounds__(256,2): VALU-issue-bound kernel -> trade occupancy (48
// VGPR @ 8 waves/SIMD) for register headroom (<=256 VGPR @ 2 blocks/CU) so
// the batched threefry keeps constants resident and interleaves its chains.
__global__ __launch_bounds__(256, 2) void attn_kernel(const u16* __restrict__ Q,
                                                      const u16* __restrict__ K,
                                                      const u16* __restrict__ Vt,
                                                      const float* __restrict__ mask,
                                                      float* __restrict__ outp) {
    // double-buffered per-wave P tile (R5-verified: asm fences + parity)
    __shared__ __align__(16) u16 Plds[2][4][16][40];
    int qt = blockIdx.x, h = blockIdx.y, b = blockIdx.z;
    int bh = b * 16 + h;
    int tid = threadIdx.x, wv = tid >> 6, lane = tid & 63;
    int quad = lane >> 4, l16 = lane & 15;
    int q0 = qt * 64 + wv * 16;

    const u16* Qb = Q + (size_t)bh * 1024 * 64;
    const u16* Kb = K + (size_t)bh * 1024 * 64;
    const u16* Vb = Vt + (size_t)bh * 64 * 1024;

    bf16x8 aq0 = *(const bf16x8*)(Qb + (q0 + l16) * 64 + quad * 8);
    bf16x8 aq1 = *(const bf16x8*)(Qb + (q0 + l16) * 64 + 32 + quad * 8);

    f32x4 oacc[4];
#pragma unroll
    for (int i = 0; i < 4; i++) oacc[i] = (f32x4){0.f, 0.f, 0.f, 0.f};
    float lsum[4] = {0.f, 0.f, 0.f, 0.f};

    u16* Pw0 = &Plds[0][wv][0][0];
    u16* Pw1 = &Plds[1][wv][0][0];
    u32 idxbase = ((u32)bh * 1024u + (u32)(q0 + quad * 4)) * 1024u;
    const float* maskb = mask + b * 1024;

    for (int ks = 0; ks < 1024; ks += 32) {
        // ---- S = Q K^T for 16 q-rows x 32 k-cols
        f32x4 s0 = (f32x4){0.f, 0.f, 0.f, 0.f};
        f32x4 s1 = (f32x4){0.f, 0.f, 0.f, 0.f};
        const u16* Kt = Kb + (size_t)ks * 64;
        bf16x8 bk0 = *(const bf16x8*)(Kt + l16 * 64 + quad * 8);
        bf16x8 bk1 = *(const bf16x8*)(Kt + l16 * 64 + 32 + quad * 8);
        bf16x8 bk2 = *(const bf16x8*)(Kt + (16 + l16) * 64 + quad * 8);
        bf16x8 bk3 = *(const bf16x8*)(Kt + (16 + l16) * 64 + 32 + quad * 8);
        s0 = MFMA16(aq0, bk0, s0);
        s0 = MFMA16(aq1, bk1, s0);
        s1 = MFMA16(aq0, bk2, s1);
        s1 = MFMA16(aq1, bk3, s1);

        int kg0 = ks + l16;
        float mk0 = maskb[kg0];
        float mk1 = maskb[kg0 + 16];

        // ---- 8 noise draws, batched (d = 2r+j; idx = base + r*1024 + j*16)
        u32 idxs[8];
        float pu[8];
#pragma unroll
        for (int r = 0; r < 4; r++) {
            u32 idx = idxbase + (u32)r * 1024u + (u32)kg0;
            idxs[2 * r] = idx;
            idxs[2 * r + 1] = idx + 16u;
        }
        noise_pu8(idxs, pu);

        u16* myP = ((ks >> 5) & 1) ? Pw1 : Pw0;
#pragma unroll
        for (int r = 0; r < 4; r++) {
            // 0.07071068 = 0.05*sqrt(2); logit = qkt/8 + noise + mask
            float sv0 = fmaf(pu[2 * r], 0.07071067811865475f, fmaf(s0[r], 0.125f, mk0));
            float sv1 = fmaf(pu[2 * r + 1], 0.07071067811865475f, fmaf(s1[r], 0.125f, mk1));
            u32 pk = pack_bf16x2(__expf(sv0), __expf(sv1));  // v_cvt_pk_bf16_f32
            myP[(quad * 4 + r) * 40 + l16] = (u16)pk;
            myP[(quad * 4 + r) * 40 + 16 + l16] = (u16)(pk >> 16);
            lsum[r] += bfbits2f(pk & 0xFFFFu) + bfbits2f(pk >> 16);
        }

        // ---- O += P V  (P read back from LDS in A-operand layout)
        asm volatile("" ::: "memory");  // writes above stay above the read
        bf16x8 pf = *(const bf16x8*)(myP + l16 * 40 + quad * 8);
        asm volatile("" ::: "memory");  // later writes stay below the read
        const u16* Vk = Vb + ks;
#pragma unroll
        for (int nt = 0; nt < 4; nt++) {
            bf16x8 vf = *(const bf16x8*)(Vk + (nt * 16 + l16) * 1024 + quad * 8);
            oacc[nt] = MFMA16(pf, vf, oacc[nt]);
        }
    }

    // ---- epilogue: reduce l over the 16 lanes of each quad, O/l, write f32
    float linv[4];
#pragma unroll
    for (int r = 0; r < 4; r++) {
        float l = lsum[r];
        l += __shfl_xor(l, 1);
        l += __shfl_xor(l, 2);
        l += __shfl_xor(l, 4);
        l += __shfl_xor(l, 8);
        linv[r] = 1.0f / l;
    }
#pragma unroll
    for (int nt = 0; nt < 4; nt++) {
#pragma unroll
        for (int r = 0; r < 4; r++) {
            int q = q0 + quad * 4 + r;
            int dh = nt * 16 + l16;
            outp[((size_t)(b * 1024 + q)) * 1024 + h * 64 + dh] = oacc[nt][r] * linv[r];
        }
    }
}

extern "C" void kernel_launch(void* const* d_in, const int* in_sizes, int n_in,
                              void* d_out, int out_size, void* d_ws, size_t ws_size,
                              hipStream_t stream) {
    (void)in_sizes; (void)n_in; (void)out_size; (void)ws_size;
    const float* hidden = (const float*)d_in[0];
    const float* maskp  = (const float*)d_in[1];
    const float* Wq     = (const float*)d_in[2];
    const float* Wk     = (const float*)d_in[3];
    const float* Wv     = (const float*)d_in[4];
    float* outp = (float*)d_out;  // reference output dtype is float32

    char* ws = (char*)d_ws;
    u32* slots = (u32*)ws;                         // 4 x u32 (f32 bits of absmax)
    u16* hq  = (u16*)(ws + 256);                   // [4096][1024] int8 vals as bf16 (8 MB)
    u16* hbf = hq + 4096 * 1024;                   // [4096][1024] raw bf16 (8 MB)
    u16* wqi = hbf + 4096 * 1024;                  // [1024][1024] int4 vals as bf16 (2 MB)
    u16* wki = wqi + 1024 * 1024;
    u16* wvi = wki + 1024 * 1024;
    u16* Qb  = wvi + 1024 * 1024;                  // [B,H,S,64] (8 MB)
    u16* Kb  = Qb + 4096 * 1024;                   // [B,H,S,64] (8 MB)
    u16* Vtb = Kb + 4096 * 1024;                   // [B,H,64,S] (8 MB)

    hipMemsetAsync(slots, 0, 16, stream);
    absmax_k<<<dim3(128, 4), 256, 0, stream>>>(hidden, Wq, Wk, Wv, slots);
    prequant_all<<<dim3(64, 4), 256, 0, stream>>>(hidden, Wq, Wk, Wv,
                                                  hq, hbf, wqi, wki, wvi, slots);
    qkv_gemm_all<<<dim3(64, 16, 3), 256, 0, stream>>>(hq, hbf, wqi, wki, wvi, slots,
                                                      Qb, Kb, Vtb);
    attn_kernel<<<dim3(16, 16, 4), 256, 0, stream>>>(Qb, Kb, Vtb, maskp, outp);
}

// Round 8
// 389.208 us; speedup vs baseline: 1.0160x; 1.0160x over previous
//
#include <hip/hip_runtime.h>
#include <hip/hip_bf16.h>

typedef unsigned short u16;
typedef unsigned int u32;
typedef __bf16 bf16x8 __attribute__((ext_vector_type(8)));
typedef float f32x4 __attribute__((ext_vector_type(4)));

#define MFMA16(a, b, c) __builtin_amdgcn_mfma_f32_16x16x32_bf16((a), (b), (c), 0, 0, 0)

static __device__ __forceinline__ float bfbits2f(u32 b) {
    union { u32 u; float f; } c; c.u = b << 16; return c.f;
}
// round-to-nearest-even f32 -> bf16 bits
static __device__ __forceinline__ u32 f2bfbits(float f) {
    union { float f; u32 u; } c; c.f = f;
    return (c.u + 0x7FFFu + ((c.u >> 16) & 1u)) >> 16;
}
// exact for small integers (|v| <= 255): low 16 mantissa bits are zero
static __device__ __forceinline__ u32 f2bfbits_exact(float f) {
    union { float f; u32 u; } c; c.f = f;
    return c.u >> 16;
}
// packed RNE f32x2 -> bf16x2
static __device__ __forceinline__ u32 pack_bf16x2(float lo, float hi) {
    float2 v; v.x = lo; v.y = hi;
    union { __hip_bfloat162 h; u32 u; } c;
    c.h = __float22bfloat162_rn(v);
    return c.u;  // low 16 = lo, high 16 = hi
}

// ---------------- batched JAX threefry2x32, key (0,42), 8 draws in lockstep.
// Partitionable mode (HW-verified R4): counter=(0,idx), bits=x0^x1,
// uniform in [-0.99999994, 1), XLA Giles erfinv; returns p*u = erfinv(u).
static __device__ __forceinline__ void noise_pu8(const u32* __restrict__ idx,
                                                 float* __restrict__ pu) {
    const u32 K1 = 42u, K2 = 0x1BD11BF0u;  // 0x1BD11BDA ^ 42
    u32 x0[8], x1[8];
#pragma unroll
    for (int d = 0; d < 8; d++) { x0[d] = 0u; x1[d] = idx[d] + K1; }
#define TFR(R)                                            \
    _Pragma("unroll") for (int d = 0; d < 8; d++) {       \
        x0[d] += x1[d];                                   \
        x1[d] = __builtin_rotateleft32(x1[d], R) ^ x0[d]; \
    }
#define INJ(A, B)                                         \
    _Pragma("unroll") for (int d = 0; d < 8; d++) {       \
        x0[d] += (A); x1[d] += (B);                       \
    }
    TFR(13) TFR(15) TFR(26) TFR(6)  INJ(K1, K2 + 1u)
    TFR(17) TFR(29) TFR(16) TFR(24) INJ(K2, 2u)
    TFR(13) TFR(15) TFR(26) TFR(6)  INJ(0u, K1 + 3u)
    TFR(17) TFR(29) TFR(16) TFR(24) INJ(K1, K2 + 4u)
    TFR(13) TFR(15) TFR(26) TFR(6)  INJ(K2, 5u)
#undef TFR
#undef INJ
#pragma unroll
    for (int d = 0; d < 8; d++) {
        u32 bits = x0[d] ^ x1[d];
        float f = __uint_as_float((bits >> 9) | 0x3F800000u) - 1.0f;  // [0,1)
        float u = fmaf(f, 2.0f, -0.99999994f);
        u = fmaxf(-0.99999994f, u);
        float t = fmaf(-u, u, 1.0f);   // exact 1-u^2 (single rounding)
        float lg = __logf(t);          // native v_log_f32 path
        float p;
        if (lg > -5.0f) {              // w = -lg < 5
            float z = fmaf(lg, -1.0f, -2.5f);
            p = 2.81022636e-08f;
            p = fmaf(p, z, 3.43273939e-07f);
            p = fmaf(p, z, -3.5233877e-06f);
            p = fmaf(p, z, -4.39150654e-06f);
            p = fmaf(p, z, 0.00021858087f);
            p = fmaf(p, z, -0.00125372503f);
            p = fmaf(p, z, -0.00417768164f);
            p = fmaf(p, z, 0.246640727f);
            p = fmaf(p, z, 1.50140941f);
        } else {
            float z = sqrtf(-lg) - 3.0f;
            p = -0.000200214257f;
            p = fmaf(p, z, 0.000100950558f);
            p = fmaf(p, z, 0.00134934322f);
            p = fmaf(p, z, -0.00367342844f);
            p = fmaf(p, z, 0.00573950773f);
            p = fmaf(p, z, -0.0076224613f);
            p = fmaf(p, z, 0.00943887047f);
            p = fmaf(p, z, 1.00167406f);
            p = fmaf(p, z, 2.83297682f);
        }
        pu[d] = p * u;  // caller: fma(pu, 0.05*sqrt(2), logit)
    }
}

// ---------------- absmax over the 4 f32 tensors (u32 bit compare, sign stripped)
__global__ __launch_bounds__(256) void absmax_k(const float* __restrict__ h,
                                                const float* __restrict__ wq,
                                                const float* __restrict__ wk,
                                                const float* __restrict__ wv,
                                                u32* __restrict__ slots) {
    int t = blockIdx.y;
    const float* src = (t == 0) ? h : (t == 1) ? wq : (t == 2) ? wk : wv;
    int n4 = ((t == 0) ? 4096 * 1024 : 1024 * 1024) / 4;
    u32 mx = 0;
    int tid = threadIdx.x;
    for (int i = blockIdx.x * blockDim.x + tid; i < n4; i += gridDim.x * blockDim.x) {
        uint4 v = ((const uint4*)src)[i];
        mx = max(mx, v.x & 0x7FFFFFFFu);
        mx = max(mx, v.y & 0x7FFFFFFFu);
        mx = max(mx, v.z & 0x7FFFFFFFu);
        mx = max(mx, v.w & 0x7FFFFFFFu);
    }
    __shared__ u32 red[256];
    red[tid] = mx;
    __syncthreads();
    for (int s = 128; s > 0; s >>= 1) {
        if (tid < s) red[tid] = max(red[tid], red[tid + s]);
        __syncthreads();
    }
    if (tid == 0) atomicMax(&slots[t], red[0]);
}

// ---------------- merged pre-quantize: y=0 hidden (8-bit, + raw bf16 copy),
// y=1..3 weights (4-bit)
__global__ __launch_bounds__(256) void prequant_all(const float* __restrict__ hidden,
                                                    const float* __restrict__ wq,
                                                    const float* __restrict__ wk,
                                                    const float* __restrict__ wv,
                                                    u16* __restrict__ hq,
                                                    u16* __restrict__ hbf,
                                                    u16* __restrict__ wqi,
                                                    u16* __restrict__ wki,
                                                    u16* __restrict__ wvi,
                                                    const u32* __restrict__ slots) {
    int y = blockIdx.y;
    const float* src = (y == 0) ? hidden : (y == 1) ? wq : (y == 2) ? wk : wv;
    u16* dqi = (y == 0) ? hq : (y == 1) ? wqi : (y == 2) ? wki : wvi;
    u16* draw = (y == 0) ? hbf : nullptr;
    float qmax = (y == 0) ? 127.0f : 7.0f;
    int n8 = ((y == 0) ? 4096 * 1024 : 1024 * 1024) / 8;

    float amax = fmaxf(__uint_as_float(slots[y]), 1e-8f);
    float scale = amax / qmax;  // IEEE f32, matches np
    for (int i = blockIdx.x * blockDim.x + threadIdx.x; i < n8; i += gridDim.x * blockDim.x) {
        float4 a = ((const float4*)src)[2 * i];
        float4 b = ((const float4*)src)[2 * i + 1];
        float x[8] = {a.x, a.y, a.z, a.w, b.x, b.y, b.z, b.w};
        u16 qi[8], rw[8];
#pragma unroll
        for (int j = 0; j < 8; j++) {
            float q = fminf(fmaxf(rintf(x[j] / scale), -qmax), qmax);  // IEEE div + half-even
            qi[j] = (u16)f2bfbits_exact(q);
            rw[j] = (u16)f2bfbits(x[j]);
        }
        *(uint4*)(dqi + 8 * (size_t)i) = *(const uint4*)qi;
        if (draw) *(uint4*)(draw + 8 * (size_t)i) = *(const uint4*)rw;
    }
}

// ---------------- merged projection GEMMs: z=0 Q, z=1 K, z=2 V^T
__global__ __launch_bounds__(256) void qkv_gemm_all(const u16* __restrict__ hq,
                                                    const u16* __restrict__ hbf,
                                                    const u16* __restrict__ wqi,
                                                    const u16* __restrict__ wki,
                                                    const u16* __restrict__ wvi,
                                                    const u32* __restrict__ slots,
                                                    u16* __restrict__ Qb,
                                                    u16* __restrict__ Kb,
                                                    u16* __restrict__ Vtb) {
    __shared__ __align__(16) u16 As[64 * 40];
    __shared__ __align__(16) u16 Bs[64 * 40];
    int z = blockIdx.z;
    const u16* A  = (z < 2) ? hq : hbf;
    const u16* Bw = (z == 0) ? wqi : (z == 1) ? wki : wvi;
    u16* outp     = (z == 0) ? Qb : (z == 1) ? Kb : Vtb;
    int transOut = (z == 2);
    float s_a = fmaxf(__uint_as_float(slots[0]), 1e-8f) / 127.0f;
    float s_w = fmaxf(__uint_as_float(slots[z + 1]), 1e-8f) / 7.0f;
    float oscale = (z < 2) ? (s_a * s_w) : s_w;

    int tid = threadIdx.x;
    int srow = tid >> 2, scol = (tid & 3) * 8;
    int mbase = blockIdx.x * 64, nbase = blockIdx.y * 64;
    int lane = tid & 63, wv = tid >> 6;
    int quad = lane >> 4, l16 = lane & 15;

    f32x4 acc[4];
#pragma unroll
    for (int i = 0; i < 4; i++) acc[i] = (f32x4){0.f, 0.f, 0.f, 0.f};

    const u16* aptr = A + (size_t)(mbase + srow) * 1024 + scol;
    const u16* bptr = Bw + (size_t)(nbase + srow) * 1024 + scol;

    for (int k0 = 0; k0 < 1024; k0 += 32) {
        uint4 av = *(const uint4*)(aptr + k0);
        uint4 bv = *(const uint4*)(bptr + k0);
        __syncthreads();
        *(uint4*)(As + srow * 40 + scol) = av;
        *(uint4*)(Bs + srow * 40 + scol) = bv;
        __syncthreads();
        bf16x8 af = *(const bf16x8*)(As + (wv * 16 + l16) * 40 + quad * 8);
#pragma unroll
        for (int nt = 0; nt < 4; nt++) {
            bf16x8 bfr = *(const bf16x8*)(Bs + (nt * 16 + l16) * 40 + quad * 8);
            acc[nt] = MFMA16(af, bfr, acc[nt]);
        }
    }

#pragma unroll
    for (int nt = 0; nt < 4; nt++) {
#pragma unroll
        for (int r = 0; r < 4; r++) {
            float val = acc[nt][r] * oscale;
            int m = mbase + wv * 16 + quad * 4 + r;  // token
            int o = nbase + nt * 16 + l16;           // out-feature
            int b = m >> 10, s = m & 1023;
            int hh = o >> 6, dh = o & 63;
            size_t off = transOut ? (((size_t)(b * 16 + hh) * 64 + dh) * 1024 + s)
                                  : (((size_t)(b * 16 + hh) * 1024 + s) * 64 + dh);
            outp[off] = (u16)f2bfbits(val);
        }
    }
}

// ---------------- split-K flash attention with inline threefry noise
// Fixed-reference softmax (M=0) => partials combine ADDITIVELY: each split
// writes unnormalized O_s and row-sums l_s; combine_k does (O0+O1)/(l0+l1).
// Grid (16,16,8): z = b + 4*split. 2048 blocks = 8 blocks/CU = 32 waves/CU
// (the HW cap) vs 16 before — doubles latency-hiding for the ~70-op
// dependent threefry chains.
__global__ __launch_bounds__(256, 2) void attn_kernel(const u16* __restrict__ Q,
                                                      const u16* __restrict__ K,
                                                      const u16* __restrict__ Vt,
                                                      const float* __restrict__ mask,
                                                      float* __restrict__ O0,
                                                      float* __restrict__ O1,
                                                      float* __restrict__ l0,
                                                      float* __restrict__ l1) {
    __shared__ __align__(16) u16 Plds[2][4][16][40];
    int qt = blockIdx.x, h = blockIdx.y;
    int b = blockIdx.z & 3, split = blockIdx.z >> 2;
    int bh = b * 16 + h;
    int tid = threadIdx.x, wv = tid >> 6, lane = tid & 63;
    int quad = lane >> 4, l16 = lane & 15;
    int q0 = qt * 64 + wv * 16;
    int ks0 = split * 512;

    float* Obuf = split ? O1 : O0;
    float* lbuf = split ? l1 : l0;

    const u16* Qb = Q + (size_t)bh * 1024 * 64;
    const u16* Kb = K + (size_t)bh * 1024 * 64;
    const u16* Vb = Vt + (size_t)bh * 64 * 1024;

    bf16x8 aq0 = *(const bf16x8*)(Qb + (q0 + l16) * 64 + quad * 8);
    bf16x8 aq1 = *(const bf16x8*)(Qb + (q0 + l16) * 64 + 32 + quad * 8);

    f32x4 oacc[4];
#pragma unroll
    for (int i = 0; i < 4; i++) oacc[i] = (f32x4){0.f, 0.f, 0.f, 0.f};
    float lsum[4] = {0.f, 0.f, 0.f, 0.f};

    u16* Pw0 = &Plds[0][wv][0][0];
    u16* Pw1 = &Plds[1][wv][0][0];
    u32 idxbase = ((u32)bh * 1024u + (u32)(q0 + quad * 4)) * 1024u;
    const float* maskb = mask + b * 1024;

    for (int ks = ks0; ks < ks0 + 512; ks += 32) {
        // ---- S = Q K^T for 16 q-rows x 32 k-cols
        f32x4 s0 = (f32x4){0.f, 0.f, 0.f, 0.f};
        f32x4 s1 = (f32x4){0.f, 0.f, 0.f, 0.f};
        const u16* Kt = Kb + (size_t)ks * 64;
        bf16x8 bk0 = *(const bf16x8*)(Kt + l16 * 64 + quad * 8);
        bf16x8 bk1 = *(const bf16x8*)(Kt + l16 * 64 + 32 + quad * 8);
        bf16x8 bk2 = *(const bf16x8*)(Kt + (16 + l16) * 64 + quad * 8);
        bf16x8 bk3 = *(const bf16x8*)(Kt + (16 + l16) * 64 + 32 + quad * 8);
        s0 = MFMA16(aq0, bk0, s0);
        s0 = MFMA16(aq1, bk1, s0);
        s1 = MFMA16(aq0, bk2, s1);
        s1 = MFMA16(aq1, bk3, s1);

        int kg0 = ks + l16;
        float mk0 = maskb[kg0];
        float mk1 = maskb[kg0 + 16];

        // ---- 8 noise draws, batched
        u32 idxs[8];
        float pu[8];
#pragma unroll
        for (int r = 0; r < 4; r++) {
            u32 idx = idxbase + (u32)r * 1024u + (u32)kg0;
            idxs[2 * r] = idx;
            idxs[2 * r + 1] = idx + 16u;
        }
        noise_pu8(idxs, pu);

        u16* myP = ((ks >> 5) & 1) ? Pw1 : Pw0;
#pragma unroll
        for (int r = 0; r < 4; r++) {
            float sv0 = fmaf(pu[2 * r], 0.07071067811865475f, fmaf(s0[r], 0.125f, mk0));
            float sv1 = fmaf(pu[2 * r + 1], 0.07071067811865475f, fmaf(s1[r], 0.125f, mk1));
            u32 pk = pack_bf16x2(__expf(sv0), __expf(sv1));
            myP[(quad * 4 + r) * 40 + l16] = (u16)pk;
            myP[(quad * 4 + r) * 40 + 16 + l16] = (u16)(pk >> 16);
            lsum[r] += bfbits2f(pk & 0xFFFFu) + bfbits2f(pk >> 16);
        }

        // ---- O += P V  (P read back from LDS in A-operand layout)
        asm volatile("" ::: "memory");  // writes above stay above the read
        bf16x8 pf = *(const bf16x8*)(myP + l16 * 40 + quad * 8);
        asm volatile("" ::: "memory");  // later writes stay below the read
        const u16* Vk = Vb + ks;
#pragma unroll
        for (int nt = 0; nt < 4; nt++) {
            bf16x8 vf = *(const bf16x8*)(Vk + (nt * 16 + l16) * 1024 + quad * 8);
            oacc[nt] = MFMA16(pf, vf, oacc[nt]);
        }
    }

    // ---- epilogue: write UNNORMALIZED O and per-row l sums
    float lred[4];
#pragma unroll
    for (int r = 0; r < 4; r++) {
        float l = lsum[r];
        l += __shfl_xor(l, 1);
        l += __shfl_xor(l, 2);
        l += __shfl_xor(l, 4);
        l += __shfl_xor(l, 8);
        lred[r] = l;
    }
    if (l16 == 0) {
        int lbase = bh * 1024 + q0 + quad * 4;
#pragma unroll
        for (int r = 0; r < 4; r++) lbuf[lbase + r] = lred[r];
    }
#pragma unroll
    for (int nt = 0; nt < 4; nt++) {
#pragma unroll
        for (int r = 0; r < 4; r++) {
            int q = q0 + quad * 4 + r;
            int dh = nt * 16 + l16;
            Obuf[((size_t)(b * 1024 + q)) * 1024 + h * 64 + dh] = oacc[nt][r];
        }
    }
}

// ---------------- combine: out = (O0 + O1) / (l0 + l1), 1 float4/thread
__global__ __launch_bounds__(256) void combine_k(float* __restrict__ outp,
                                                 const float* __restrict__ O1,
                                                 const float* __restrict__ l0,
                                                 const float* __restrict__ l1) {
    int gid = blockIdx.x * 256 + threadIdx.x;  // 1,048,576 float4s
    int e = gid << 2;
    int bq = e >> 10;                 // b*1024 + q
    int h = (e & 1023) >> 6;
    int b = bq >> 10, q = bq & 1023;
    int lidx = ((b * 16 + h) << 10) + q;
    float linv = 1.0f / (l0[lidx] + l1[lidx]);
    float4 a = ((const float4*)outp)[gid];
    float4 c = ((const float4*)O1)[gid];
    float4 o;
    o.x = (a.x + c.x) * linv;
    o.y = (a.y + c.y) * linv;
    o.z = (a.z + c.z) * linv;
    o.w = (a.w + c.w) * linv;
    ((float4*)outp)[gid] = o;
}

extern "C" void kernel_launch(void* const* d_in, const int* in_sizes, int n_in,
                              void* d_out, int out_size, void* d_ws, size_t ws_size,
                              hipStream_t stream) {
    (void)in_sizes; (void)n_in; (void)out_size; (void)ws_size;
    const float* hidden = (const float*)d_in[0];
    const float* maskp  = (const float*)d_in[1];
    const float* Wq     = (const float*)d_in[2];
    const float* Wk     = (const float*)d_in[3];
    const float* Wv     = (const float*)d_in[4];
    float* outp = (float*)d_out;  // reference output dtype is float32

    char* ws = (char*)d_ws;
    u32* slots = (u32*)ws;                         // 4 x u32 (f32 bits of absmax)
    u16* hq  = (u16*)(ws + 256);                   // [4096][1024] int8 vals as bf16 (8 MB)
    u16* hbf = hq + 4096 * 1024;                   // [4096][1024] raw bf16 (8 MB)
    u16* wqi = hbf + 4096 * 1024;                  // [1024][1024] int4 vals as bf16 (2 MB)
    u16* wki = wqi + 1024 * 1024;
    u16* wvi = wki + 1024 * 1024;
    u16* Qb  = wvi + 1024 * 1024;                  // [B,H,S,64] (8 MB)
    u16* Kb  = Qb + 4096 * 1024;                   // [B,H,S,64] (8 MB)
    u16* Vtb = Kb + 4096 * 1024;                   // [B,H,64,S] (8 MB)

    // dead-after-GEMM regions reused by split-K attention:
    float* O1buf = (float*)hq;                     // 16 MB over hq+hbf
    float* l0buf = (float*)wqi;                    // 256 KB (B*H*S f32)
    float* l1buf = l0buf + 4 * 16 * 1024;          // next 256 KB

    hipMemsetAsync(slots, 0, 16, stream);
    absmax_k<<<dim3(128, 4), 256, 0, stream>>>(hidden, Wq, Wk, Wv, slots);
    prequant_all<<<dim3(64, 4), 256, 0, stream>>>(hidden, Wq, Wk, Wv,
                                                  hq, hbf, wqi, wki, wvi, slots);
    qkv_gemm_all<<<dim3(64, 16, 3), 256, 0, stream>>>(hq, hbf, wqi, wki, wvi, slots,
                                                      Qb, Kb, Vtb);
    attn_kernel<<<dim3(16, 16, 8), 256, 0, stream>>>(Qb, Kb, Vtb, maskp,
                                                     outp, O1buf, l0buf, l1buf);
    combine_k<<<dim3(4096), 256, 0, stream>>>(outp, O1buf, l0buf, l1buf);
}

// Round 9
// 350.357 us; speedup vs baseline: 1.1287x; 1.1109x over previous
//
#include <hip/hip_runtime.h>
#include <hip/hip_bf16.h>

typedef unsigned short u16;
typedef unsigned int u32;
typedef __bf16 bf16x8 __attribute__((ext_vector_type(8)));
typedef float f32x4 __attribute__((ext_vector_type(4)));

#define MFMA16(a, b, c) __builtin_amdgcn_mfma_f32_16x16x32_bf16((a), (b), (c), 0, 0, 0)

static __device__ __forceinline__ float bfbits2f(u32 b) {
    union { u32 u; float f; } c; c.u = b << 16; return c.f;
}
// round-to-nearest-even f32 -> bf16 bits
static __device__ __forceinline__ u32 f2bfbits(float f) {
    union { float f; u32 u; } c; c.f = f;
    return (c.u + 0x7FFFu + ((c.u >> 16) & 1u)) >> 16;
}
// exact for small integers (|v| <= 255): low 16 mantissa bits are zero
static __device__ __forceinline__ u32 f2bfbits_exact(float f) {
    union { float f; u32 u; } c; c.f = f;
    return c.u >> 16;
}
// packed RNE f32x2 -> bf16x2
static __device__ __forceinline__ u32 pack_bf16x2(float lo, float hi) {
    float2 v; v.x = lo; v.y = hi;
    union { __hip_bfloat162 h; u32 u; } c;
    c.h = __float22bfloat162_rn(v);
    return c.u;  // low 16 = lo, high 16 = hi
}

// ---------------- batched JAX threefry2x32, key (0,42), 8 draws in lockstep.
// Partitionable mode (HW-verified R4): counter=(0,idx), bits=x0^x1.
// Trims vs R7 (all canaried by absmax):
//  - uniform: as_float(0x40000000|m)-3.0f is Sterbenz-exact 2f-1 (shifts u by
//    2^-24 vs XLA's lo=-(1-2^-24): noise delta ~2e-7; u=-1 corner absorbed
//    by the w-clamp below). Drops sub+fma+max -> one sub.
//  - tail branch removed: w clamped to <=5, main Giles poly only. Affects
//    2.6% of draws (|noise| capped 0.149 vs true <=0.23); output effect
//    ~2e-5 (sum over ~30 rare logits with p~1e-3). The else-path used to
//    execute EVERY wave-iter (P(any of 512 draws in tail) ~ 1).
//  - __log2f + fold ln2 into the z-fma (drops the ln2 multiply).
static __device__ __forceinline__ void noise_pu8(const u32* __restrict__ idx,
                                                 float* __restrict__ pu) {
    const u32 K1 = 42u, K2 = 0x1BD11BF0u;  // 0x1BD11BDA ^ 42
    u32 x0[8], x1[8];
#pragma unroll
    for (int d = 0; d < 8; d++) { x0[d] = 0u; x1[d] = idx[d] + K1; }
#define TFR(R)                                            \
    _Pragma("unroll") for (int d = 0; d < 8; d++) {       \
        x0[d] += x1[d];                                   \
        x1[d] = __builtin_rotateleft32(x1[d], R) ^ x0[d]; \
    }
#define INJ(A, B)                                         \
    _Pragma("unroll") for (int d = 0; d < 8; d++) {       \
        x0[d] += (A); x1[d] += (B);                       \
    }
    TFR(13) TFR(15) TFR(26) TFR(6)  INJ(K1, K2 + 1u)
    TFR(17) TFR(29) TFR(16) TFR(24) INJ(K2, 2u)
    TFR(13) TFR(15) TFR(26) TFR(6)  INJ(0u, K1 + 3u)
    TFR(17) TFR(29) TFR(16) TFR(24) INJ(K1, K2 + 4u)
    TFR(13) TFR(15) TFR(26) TFR(6)  INJ(K2, 5u)
#undef TFR
#undef INJ
#pragma unroll
    for (int d = 0; d < 8; d++) {
        u32 bits = x0[d] ^ x1[d];
        float v2 = __uint_as_float((bits >> 9) | 0x40000000u);  // 2+2f in [2,4)
        float u = v2 - 3.0f;             // exact 2f-1 (Sterbenz)
        float t = fmaf(-u, u, 1.0f);     // exact 1-u^2 (single rounding)
        float L2 = __log2f(t);           // v_log_f32; -inf at u=-1 ok (clamped)
        L2 = fmaxf(L2, -7.2134752f);     // w = -ln t <= 5  (5/ln2)
        float z = fmaf(L2, -0.69314718f, -2.5f);  // w - 2.5 in [-2.5, 2.5]
        float p = 2.81022636e-08f;
        p = fmaf(p, z, 3.43273939e-07f);
        p = fmaf(p, z, -3.5233877e-06f);
        p = fmaf(p, z, -4.39150654e-06f);
        p = fmaf(p, z, 0.00021858087f);
        p = fmaf(p, z, -0.00125372503f);
        p = fmaf(p, z, -0.00417768164f);
        p = fmaf(p, z, 0.246640727f);
        p = fmaf(p, z, 1.50140941f);
        pu[d] = p * u;  // erfinv(u); caller: fma(pu, 0.05*sqrt(2), logit)
    }
}

// ---------------- absmax over the 4 f32 tensors (u32 bit compare, sign stripped)
__global__ __launch_bounds__(256) void absmax_k(const float* __restrict__ h,
                                                const float* __restrict__ wq,
                                                const float* __restrict__ wk,
                                                const float* __restrict__ wv,
                                                u32* __restrict__ slots) {
    int t = blockIdx.y;
    const float* src = (t == 0) ? h : (t == 1) ? wq : (t == 2) ? wk : wv;
    int n4 = ((t == 0) ? 4096 * 1024 : 1024 * 1024) / 4;
    u32 mx = 0;
    int tid = threadIdx.x;
    for (int i = blockIdx.x * blockDim.x + tid; i < n4; i += gridDim.x * blockDim.x) {
        uint4 v = ((const uint4*)src)[i];
        mx = max(mx, v.x & 0x7FFFFFFFu);
        mx = max(mx, v.y & 0x7FFFFFFFu);
        mx = max(mx, v.z & 0x7FFFFFFFu);
        mx = max(mx, v.w & 0x7FFFFFFFu);
    }
    __shared__ u32 red[256];
    red[tid] = mx;
    __syncthreads();
    for (int s = 128; s > 0; s >>= 1) {
        if (tid < s) red[tid] = max(red[tid], red[tid + s]);
        __syncthreads();
    }
    if (tid == 0) atomicMax(&slots[t], red[0]);
}

// ---------------- merged pre-quantize: y=0 hidden (8-bit, + raw bf16 copy),
// y=1..3 weights (4-bit)
__global__ __launch_bounds__(256) void prequant_all(const float* __restrict__ hidden,
                                                    const float* __restrict__ wq,
                                                    const float* __restrict__ wk,
                                                    const float* __restrict__ wv,
                                                    u16* __restrict__ hq,
                                                    u16* __restrict__ hbf,
                                                    u16* __restrict__ wqi,
                                                    u16* __restrict__ wki,
                                                    u16* __restrict__ wvi,
                                                    const u32* __restrict__ slots) {
    int y = blockIdx.y;
    const float* src = (y == 0) ? hidden : (y == 1) ? wq : (y == 2) ? wk : wv;
    u16* dqi = (y == 0) ? hq : (y == 1) ? wqi : (y == 2) ? wki : wvi;
    u16* draw = (y == 0) ? hbf : nullptr;
    float qmax = (y == 0) ? 127.0f : 7.0f;
    int n8 = ((y == 0) ? 4096 * 1024 : 1024 * 1024) / 8;

    float amax = fmaxf(__uint_as_float(slots[y]), 1e-8f);
    float scale = amax / qmax;  // IEEE f32, matches np
    for (int i = blockIdx.x * blockDim.x + threadIdx.x; i < n8; i += gridDim.x * blockDim.x) {
        float4 a = ((const float4*)src)[2 * i];
        float4 b = ((const float4*)src)[2 * i + 1];
        float x[8] = {a.x, a.y, a.z, a.w, b.x, b.y, b.z, b.w};
        u16 qi[8], rw[8];
#pragma unroll
        for (int j = 0; j < 8; j++) {
            float q = fminf(fmaxf(rintf(x[j] / scale), -qmax), qmax);  // IEEE div + half-even
            qi[j] = (u16)f2bfbits_exact(q);
            rw[j] = (u16)f2bfbits(x[j]);
        }
        *(uint4*)(dqi + 8 * (size_t)i) = *(const uint4*)qi;
        if (draw) *(uint4*)(draw + 8 * (size_t)i) = *(const uint4*)rw;
    }
}

// ---------------- merged projection GEMMs, 128x128 tile (m93-class):
// z=0 Q, z=1 K, z=2 V^T. Grid (32, 8, 3), 256 thr = 4 waves (2x2), each wave
// a 64x64 subtile via 4x4 MFMA 16x16x32 frags. Per K-iter: 4 staged uint4
// loads/thread, 8 ds_read_b128 + 16 MFMA per wave.
__global__ __launch_bounds__(256, 2) void qkv_gemm_all(const u16* __restrict__ hq,
                                                       const u16* __restrict__ hbf,
                                                       const u16* __restrict__ wqi,
                                                       const u16* __restrict__ wki,
                                                       const u16* __restrict__ wvi,
                                                       const u32* __restrict__ slots,
                                                       u16* __restrict__ Qb,
                                                       u16* __restrict__ Kb,
                                                       u16* __restrict__ Vtb) {
    __shared__ __align__(16) u16 As[128 * 40];
    __shared__ __align__(16) u16 Bs[128 * 40];
    int z = blockIdx.z;
    const u16* A  = (z < 2) ? hq : hbf;
    const u16* Bw = (z == 0) ? wqi : (z == 1) ? wki : wvi;
    u16* outp     = (z == 0) ? Qb : (z == 1) ? Kb : Vtb;
    int transOut = (z == 2);
    float s_a = fmaxf(__uint_as_float(slots[0]), 1e-8f) / 127.0f;
    float s_w = fmaxf(__uint_as_float(slots[z + 1]), 1e-8f) / 7.0f;
    float oscale = (z < 2) ? (s_a * s_w) : s_w;

    int tid = threadIdx.x;
    int srow = tid >> 2, scol = (tid & 3) * 8;   // staging: 2 rows/thread (+0,+64)
    int mbase = blockIdx.x * 128, nbase = blockIdx.y * 128;
    int lane = tid & 63, w = tid >> 6;
    int wv_m = w & 1, wv_n = w >> 1;
    int quad = lane >> 4, l16 = lane & 15;

    f32x4 acc[4][4];
#pragma unroll
    for (int i = 0; i < 4; i++)
#pragma unroll
        for (int j = 0; j < 4; j++) acc[i][j] = (f32x4){0.f, 0.f, 0.f, 0.f};

    const u16* aptr0 = A + (size_t)(mbase + srow) * 1024 + scol;
    const u16* aptr1 = A + (size_t)(mbase + 64 + srow) * 1024 + scol;
    const u16* bptr0 = Bw + (size_t)(nbase + srow) * 1024 + scol;
    const u16* bptr1 = Bw + (size_t)(nbase + 64 + srow) * 1024 + scol;

    for (int k0 = 0; k0 < 1024; k0 += 32) {
        uint4 a0 = *(const uint4*)(aptr0 + k0);
        uint4 a1 = *(const uint4*)(aptr1 + k0);
        uint4 b0 = *(const uint4*)(bptr0 + k0);
        uint4 b1 = *(const uint4*)(bptr1 + k0);
        __syncthreads();
        *(uint4*)(As + srow * 40 + scol) = a0;
        *(uint4*)(As + (64 + srow) * 40 + scol) = a1;
        *(uint4*)(Bs + srow * 40 + scol) = b0;
        *(uint4*)(Bs + (64 + srow) * 40 + scol) = b1;
        __syncthreads();
        bf16x8 af[4], bfr[4];
#pragma unroll
        for (int mt = 0; mt < 4; mt++)
            af[mt] = *(const bf16x8*)(As + (wv_m * 64 + mt * 16 + l16) * 40 + quad * 8);
#pragma unroll
        for (int nt = 0; nt < 4; nt++)
            bfr[nt] = *(const bf16x8*)(Bs + (wv_n * 64 + nt * 16 + l16) * 40 + quad * 8);
#pragma unroll
        for (int mt = 0; mt < 4; mt++)
#pragma unroll
            for (int nt = 0; nt < 4; nt++)
                acc[mt][nt] = MFMA16(af[mt], bfr[nt], acc[mt][nt]);
    }

#pragma unroll
    for (int mt = 0; mt < 4; mt++)
#pragma unroll
        for (int nt = 0; nt < 4; nt++)
#pragma unroll
            for (int r = 0; r < 4; r++) {
                float val = acc[mt][nt][r] * oscale;
                int m = mbase + wv_m * 64 + mt * 16 + quad * 4 + r;  // token
                int o = nbase + wv_n * 64 + nt * 16 + l16;           // out-feature
                int b = m >> 10, s = m & 1023;
                int hh = o >> 6, dh = o & 63;
                size_t off = transOut ? (((size_t)(b * 16 + hh) * 64 + dh) * 1024 + s)
                                      : (((size_t)(b * 16 + hh) * 1024 + s) * 64 + dh);
                outp[off] = (u16)f2bfbits(val);
            }
}

// ---------------- split-K flash attention with inline threefry noise
// Fixed-reference softmax (M=0) => partials combine ADDITIVELY.
__global__ __launch_bounds__(256, 2) void attn_kernel(const u16* __restrict__ Q,
                                                      const u16* __restrict__ K,
                                                      const u16* __restrict__ Vt,
                                                      const float* __restrict__ mask,
                                                      float* __restrict__ O0,
                                                      float* __restrict__ O1,
                                                      float* __restrict__ l0,
                                                      float* __restrict__ l1) {
    __shared__ __align__(16) u16 Plds[2][4][16][40];
    int qt = blockIdx.x, h = blockIdx.y;
    int b = blockIdx.z & 3, split = blockIdx.z >> 2;
    int bh = b * 16 + h;
    int tid = threadIdx.x, wv = tid >> 6, lane = tid & 63;
    int quad = lane >> 4, l16 = lane & 15;
    int q0 = qt * 64 + wv * 16;
    int ks0 = split * 512;

    float* Obuf = split ? O1 : O0;
    float* lbuf = split ? l1 : l0;

    const u16* Qb = Q + (size_t)bh * 1024 * 64;
    const u16* Kb = K + (size_t)bh * 1024 * 64;
    const u16* Vb = Vt + (size_t)bh * 64 * 1024;

    bf16x8 aq0 = *(const bf16x8*)(Qb + (q0 + l16) * 64 + quad * 8);
    bf16x8 aq1 = *(const bf16x8*)(Qb + (q0 + l16) * 64 + 32 + quad * 8);

    f32x4 oacc[4];
#pragma unroll
    for (int i = 0; i < 4; i++) oacc[i] = (f32x4){0.f, 0.f, 0.f, 0.f};
    float lsum[4] = {0.f, 0.f, 0.f, 0.f};

    u16* Pw0 = &Plds[0][wv][0][0];
    u16* Pw1 = &Plds[1][wv][0][0];
    u32 idxbase = ((u32)bh * 1024u + (u32)(q0 + quad * 4)) * 1024u;
    const float* maskb = mask + b * 1024;

    for (int ks = ks0; ks < ks0 + 512; ks += 32) {
        // ---- S = Q K^T for 16 q-rows x 32 k-cols
        f32x4 s0 = (f32x4){0.f, 0.f, 0.f, 0.f};
        f32x4 s1 = (f32x4){0.f, 0.f, 0.f, 0.f};
        const u16* Kt = Kb + (size_t)ks * 64;
        bf16x8 bk0 = *(const bf16x8*)(Kt + l16 * 64 + quad * 8);
        bf16x8 bk1 = *(const bf16x8*)(Kt + l16 * 64 + 32 + quad * 8);
        bf16x8 bk2 = *(const bf16x8*)(Kt + (16 + l16) * 64 + quad * 8);
        bf16x8 bk3 = *(const bf16x8*)(Kt + (16 + l16) * 64 + 32 + quad * 8);
        s0 = MFMA16(aq0, bk0, s0);
        s0 = MFMA16(aq1, bk1, s0);
        s1 = MFMA16(aq0, bk2, s1);
        s1 = MFMA16(aq1, bk3, s1);

        int kg0 = ks + l16;
        float mk0 = maskb[kg0];
        float mk1 = maskb[kg0 + 16];

        // ---- 8 noise draws, batched
        u32 idxs[8];
        float pu[8];
#pragma unroll
        for (int r = 0; r < 4; r++) {
            u32 idx = idxbase + (u32)r * 1024u + (u32)kg0;
            idxs[2 * r] = idx;
            idxs[2 * r + 1] = idx + 16u;
        }
        noise_pu8(idxs, pu);

        u16* myP = ((ks >> 5) & 1) ? Pw1 : Pw0;
#pragma unroll
        for (int r = 0; r < 4; r++) {
            float sv0 = fmaf(pu[2 * r], 0.07071067811865475f, fmaf(s0[r], 0.125f, mk0));
            float sv1 = fmaf(pu[2 * r + 1], 0.07071067811865475f, fmaf(s1[r], 0.125f, mk1));
            float e0 = __expf(sv0);
            float e1 = __expf(sv1);
            u32 pk = pack_bf16x2(e0, e1);
            myP[(quad * 4 + r) * 40 + l16] = (u16)pk;
            myP[(quad * 4 + r) * 40 + 16 + l16] = (u16)(pk >> 16);
            lsum[r] += e0 + e1;  // pre-round sum: rel err ~6e-5, negligible
        }

        // ---- O += P V  (P read back from LDS in A-operand layout)
        asm volatile("" ::: "memory");  // writes above stay above the read
        bf16x8 pf = *(const bf16x8*)(myP + l16 * 40 + quad * 8);
        asm volatile("" ::: "memory");  // later writes stay below the read
        const u16* Vk = Vb + ks;
#pragma unroll
        for (int nt = 0; nt < 4; nt++) {
            bf16x8 vf = *(const bf16x8*)(Vk + (nt * 16 + l16) * 1024 + quad * 8);
            oacc[nt] = MFMA16(pf, vf, oacc[nt]);
        }
    }

    // ---- epilogue: write UNNORMALIZED O and per-row l sums
    float lred[4];
#pragma unroll
    for (int r = 0; r < 4; r++) {
        float l = lsum[r];
        l += __shfl_xor(l, 1);
        l += __shfl_xor(l, 2);
        l += __shfl_xor(l, 4);
        l += __shfl_xor(l, 8);
        lred[r] = l;
    }
    if (l16 == 0) {
        int lbase = bh * 1024 + q0 + quad * 4;
#pragma unroll
        for (int r = 0; r < 4; r++) lbuf[lbase + r] = lred[r];
    }
#pragma unroll
    for (int nt = 0; nt < 4; nt++) {
#pragma unroll
        for (int r = 0; r < 4; r++) {
            int q = q0 + quad * 4 + r;
            int dh = nt * 16 + l16;
            Obuf[((size_t)(b * 1024 + q)) * 1024 + h * 64 + dh] = oacc[nt][r];
        }
    }
}

// ---------------- combine: out = (O0 + O1) / (l0 + l1), 1 float4/thread
__global__ __launch_bounds__(256) void combine_k(float* __restrict__ outp,
                                                 const float* __restrict__ O1,
                                                 const float* __restrict__ l0,
                                                 const float* __restrict__ l1) {
    int gid = blockIdx.x * 256 + threadIdx.x;  // 1,048,576 float4s
    int e = gid << 2;
    int bq = e >> 10;                 // b*1024 + q
    int h = (e & 1023) >> 6;
    int b = bq >> 10, q = bq & 1023;
    int lidx = ((b * 16 + h) << 10) + q;
    float linv = 1.0f / (l0[lidx] + l1[lidx]);
    float4 a = ((const float4*)outp)[gid];
    float4 c = ((const float4*)O1)[gid];
    float4 o;
    o.x = (a.x + c.x) * linv;
    o.y = (a.y + c.y) * linv;
    o.z = (a.z + c.z) * linv;
    o.w = (a.w + c.w) * linv;
    ((float4*)outp)[gid] = o;
}

extern "C" void kernel_launch(void* const* d_in, const int* in_sizes, int n_in,
                              void* d_out, int out_size, void* d_ws, size_t ws_size,
                              hipStream_t stream) {
    (void)in_sizes; (void)n_in; (void)out_size; (void)ws_size;
    const float* hidden = (const float*)d_in[0];
    const float* maskp  = (const float*)d_in[1];
    const float* Wq     = (const float*)d_in[2];
    const float* Wk     = (const float*)d_in[3];
    const float* Wv     = (const float*)d_in[4];
    float* outp = (float*)d_out;  // reference output dtype is float32

    char* ws = (char*)d_ws;
    u32* slots = (u32*)ws;                         // 4 x u32 (f32 bits of absmax)
    u16* hq  = (u16*)(ws + 256);                   // [4096][1024] int8 vals as bf16 (8 MB)
    u16* hbf = hq + 4096 * 1024;                   // [4096][1024] raw bf16 (8 MB)
    u16* wqi = hbf + 4096 * 1024;                  // [1024][1024] int4 vals as bf16 (2 MB)
    u16* wki = wqi + 1024 * 1024;
    u16* wvi = wki + 1024 * 1024;
    u16* Qb  = wvi + 1024 * 1024;                  // [B,H,S,64] (8 MB)
    u16* Kb  = Qb + 4096 * 1024;                   // [B,H,S,64] (8 MB)
    u16* Vtb = Kb + 4096 * 1024;                   // [B,H,64,S] (8 MB)

    // dead-after-GEMM regions reused by split-K attention:
    float* O1buf = (float*)hq;                     // 16 MB over hq+hbf
    float* l0buf = (float*)wqi;                    // 256 KB (B*H*S f32)
    float* l1buf = l0buf + 4 * 16 * 1024;          // next 256 KB

    hipMemsetAsync(slots, 0, 16, stream);
    absmax_k<<<dim3(128, 4), 256, 0, stream>>>(hidden, Wq, Wk, Wv, slots);
    prequant_all<<<dim3(64, 4), 256, 0, stream>>>(hidden, Wq, Wk, Wv,
                                                  hq, hbf, wqi, wki, wvi, slots);
    qkv_gemm_all<<<dim3(32, 8, 3), 256, 0, stream>>>(hq, hbf, wqi, wki, wvi, slots,
                                                     Qb, Kb, Vtb);
    attn_kernel<<<dim3(16, 16, 8), 256, 0, stream>>>(Qb, Kb, Vtb, maskp,
                                                     outp, O1buf, l0buf, l1buf);
    combine_k<<<dim3(4096), 256, 0, stream>>>(outp, O1buf, l0buf, l1buf);
}